// Round 5
// baseline (322.124 us; speedup 1.0000x reference)
//
#include <hip/hip_runtime.h>
#include <hip/hip_cooperative_groups.h>
#include <math.h>

namespace cg = cooperative_groups;

#define EE 300
#define KP 320     // bf16 row stride (10 k-steps of 32)
#define LDSW 328   // padded LDS row stride in shorts
#define QQ 64
#define DD 4096
#define NEG 0.01f
#define GRID 512   // 2 blocks/CU guaranteed co-resident

typedef __attribute__((ext_vector_type(8))) short short8;
typedef __attribute__((ext_vector_type(4))) float f32x4;
typedef unsigned short ushort_t;

#define GATHER_ROWS (66 + 4098 + 4098)           // 8262
#define GATHER_BLOCKS ((GATHER_ROWS + 3) / 4)    // 2066
#define WT_BLOCKS 143
#define TR_BLOCKS 128
#define ZERO_BLOCKS 9
#define N0 (GATHER_BLOCKS + WT_BLOCKS + TR_BLOCKS + ZERO_BLOCKS)  // 2346
#define N1 516
#define N2 512
#define N3 384
#define SMEM_BYTES (34 * LDSW * 2)               // 22304 B, max over all phases

struct Params {
  const float *emb, *conv_w, *conv_b, *qw_w, *qw_b, *doc1_sim, *doc2_sim;
  const float *idf, *lin1_w, *lin2_w, *out_w, *gaf, *baf;
  const int *question, *doc1, *doc2;
  ushort_t *qbe, *d1be, *d2be, *qbc, *d1bc, *d2bc, *wt2;
  float *ohT1, *ohT2, *sims;
  float *nq2, *nd12, *nd22;
  float *nqc2, *nd1c2, *nd2c2, *qwacc, *pool;   // nqc2.. contiguous zero block
  float *out5;
};

__device__ inline ushort_t f2bf(float f) {
  unsigned u = __builtin_bit_cast(unsigned, f);
  u += 0x7fff + ((u >> 16) & 1);   // RNE
  return (ushort_t)(u >> 16);
}
__device__ inline float bf2f(ushort_t h) {
  return __builtin_bit_cast(float, (unsigned)h << 16);
}
__device__ inline void top5_insert(float* t, float v) {
  if (v > t[4]) {
    t[4] = v;
    #pragma unroll
    for (int j = 4; j > 0; --j)
      if (t[j] > t[j - 1]) { float tmp = t[j]; t[j] = t[j - 1]; t[j - 1] = tmp; }
  }
}

// ============ phase 0: gather+convert | wtrans | oh transpose | zero ========
__device__ void phase0_task(const Params& P, char* smem, int task, int tid) {
  int wv = tid >> 6, lane = tid & 63;
  if (task < GATHER_BLOCKS) {
    int g = task * 4 + wv;
    if (g >= GATHER_ROWS) return;
    int t, row;
    if (g < 66)             { t = 0; row = g; }
    else if (g < 66 + 4098) { t = 1; row = g - 66; }
    else                    { t = 2; row = g - 4164; }
    const int* idx = t == 0 ? P.question : (t == 1 ? P.doc1 : P.doc2);
    int L = t == 0 ? QQ : DD;
    ushort_t* be = t == 0 ? P.qbe : (t == 1 ? P.d1be : P.d2be);
    ushort_t* bc = t == 0 ? P.qbc : (t == 1 ? P.d1bc : P.d2bc);
    float* nrm2 = t == 0 ? P.nq2 : (t == 1 ? P.nd12 : P.nd22);
    if (row == 0 || row == L + 1) {            // zero guard rows
      for (int i = lane; i < KP; i += 64) be[(size_t)row * KP + i] = 0;
      return;
    }
    int r = row - 1;
    const float* src = P.emb + (size_t)idx[r] * EE;
    float ss = 0.f;
    for (int i = lane; i < EE; i += 64) {
      float v = src[i];
      be[(size_t)row * KP + i] = f2bf(v);
      ss += v * v;
    }
    for (int i = EE + lane; i < KP; i += 64) {   // zero K-pads
      be[(size_t)row * KP + i] = 0;
      bc[(size_t)r * KP + i] = 0;
    }
    #pragma unroll
    for (int o = 32; o; o >>= 1) ss += __shfl_xor(ss, o);
    if (lane == 0) nrm2[r] = ss;                 // SQUARED norm
  } else if (task < GATHER_BLOCKS + WT_BLOCKS) {
    int f = (task - GATHER_BLOCKS) * 4 + wv;
    if (f >= 570) return;
    int ks = f % 10, n = (f / 10) % 19, tap = f / 190;
    int o = n * 16 + (lane & 15);
    int kbase = ks * 32 + (lane >> 4) * 8;
    ushort_t* dst = P.wt2 + (size_t)f * 512 + lane * 8;
    #pragma unroll
    for (int e = 0; e < 8; ++e) {
      int k = kbase + e;
      float v = (o < EE && k < EE) ? P.conv_w[((size_t)o * EE + k) * 3 + tap] : 0.f;
      dst[e] = f2bf(v);
    }
  } else if (task < GATHER_BLOCKS + WT_BLOCKS + TR_BLOCKS) {
    float (*tb)[65] = (float(*)[65])smem;
    int idx2 = task - (GATHER_BLOCKS + WT_BLOCKS);
    int srcsel = idx2 >> 6, tile = idx2 & 63;
    const float* in = srcsel ? P.doc2_sim : P.doc1_sim;   // [D][Q]
    float* outT = srcsel ? P.ohT2 : P.ohT1;               // [Q][D]
    int c = tid & 63, rq = tid >> 6;
    #pragma unroll 4
    for (int i = 0; i < 16; ++i) {
      int r = i * 4 + rq;
      tb[r][c] = in[(size_t)(tile * 64 + r) * QQ + c];
    }
    __syncthreads();
    #pragma unroll 4
    for (int i = 0; i < 16; ++i) {
      int q = i * 4 + rq;
      outT[(size_t)q * DD + tile * 64 + c] = tb[c][q];
    }
    __syncthreads();
  } else {
    int i0 = (task - (GATHER_BLOCKS + WT_BLOCKS + TR_BLOCKS)) * 1024 + tid;
    #pragma unroll
    for (int j = 0; j < 4; ++j) {
      int i = i0 + j * 256;
      if (i < 8320) P.nqc2[i] = 0.f;   // nqc2,nd1c2,nd2c2,qwacc contiguous
    }
  }
}

// ====== phase 1: conv1d(E,E,3,SAME)+bias+leaky+residual + norms^2 + qw-dot ==
__device__ void phase1_task(const Params& P, char* smem, int task, int tid) {
  ushort_t* lds = (ushort_t*)smem;
  int t, m0, yh;
  if (task < 4) { t = 0; m0 = (task >> 1) * 32; yh = task & 1; }
  else {
    int i = task - 4;
    t = 1 + (i >> 8);
    int j = i & 255;
    m0 = (j >> 1) * 32; yh = j & 1;
  }
  const ushort_t* be = t == 0 ? P.qbe : (t == 1 ? P.d1be : P.d2be);
  ushort_t* bc = t == 0 ? P.qbc : (t == 1 ? P.d1bc : P.d2bc);
  float* nc2 = t == 0 ? P.nqc2 : (t == 1 ? P.nd1c2 : P.nd2c2);
  for (int s = tid; s < 34 * 40; s += 256) {
    int row = s / 40, col = s - row * 40;
    *(short8*)(&lds[row * LDSW + col * 8]) =
        *(const short8*)(be + (size_t)(m0 + row) * KP + col * 8);
  }
  __syncthreads();
  int wv = tid >> 6, lane = tid & 63, mrow = lane & 15, g = lane >> 4;
  int nstart, ncnt;
  if (yh == 0) { nstart = (wv < 2) ? 3 * wv : 2 * wv + 2; ncnt = (wv < 2) ? 3 : 2; }
  else         { nstart = (wv == 0) ? 10 : 2 * wv + 11;   ncnt = (wv == 0) ? 3 : 2; }
  f32x4 acc[3][2];
  #pragma unroll
  for (int j = 0; j < 3; ++j)
    #pragma unroll
    for (int h = 0; h < 2; ++h) acc[j][h] = (f32x4){0.f, 0.f, 0.f, 0.f};

  for (int tap = 0; tap < 3; ++tap) {
    const ushort_t* alo = &lds[(mrow + tap) * LDSW + g * 8];
    #pragma unroll
    for (int ks = 0; ks < 10; ++ks) {
      short8 a0 = *(const short8*)(alo + ks * 32);
      short8 a1 = *(const short8*)(alo + 16 * LDSW + ks * 32);
      #pragma unroll
      for (int j = 0; j < 3; ++j) {
        if (j < ncnt) {
          short8 bfr = *(const short8*)(P.wt2 +
              (size_t)((tap * 19 + nstart + j) * 10 + ks) * 512 + lane * 8);
          acc[j][0] = __builtin_amdgcn_mfma_f32_16x16x32_bf16(a0, bfr, acc[j][0], 0, 0, 0);
          acc[j][1] = __builtin_amdgcn_mfma_f32_16x16x32_bf16(a1, bfr, acc[j][1], 0, 0, 0);
        }
      }
    }
  }
  float ss[2][4] = {{0.f,0.f,0.f,0.f},{0.f,0.f,0.f,0.f}};
  float yq[2][4] = {{0.f,0.f,0.f,0.f},{0.f,0.f,0.f,0.f}};
  #pragma unroll
  for (int j = 0; j < 3; ++j) {
    if (j < ncnt) {
      int col = (nstart + j) * 16 + mrow;
      if (col < EE) {
        float bcol = P.conv_b[col];
        float qwc = (t == 0) ? P.qw_w[col] : 0.f;
        #pragma unroll
        for (int h = 0; h < 2; ++h) {
          #pragma unroll
          for (int r = 0; r < 4; ++r) {
            int lrow = h * 16 + g * 4 + r;
            float y = acc[j][h][r] + bcol;
            y = (y >= 0.f) ? y : NEG * y;
            y += bf2f(lds[(1 + lrow) * LDSW + col]);
            bc[(size_t)(m0 + lrow) * KP + col] = f2bf(y);
            ss[h][r] += y * y;
            if (t == 0) yq[h][r] += y * qwc;
          }
        }
      }
    }
  }
  #pragma unroll
  for (int h = 0; h < 2; ++h) {
    #pragma unroll
    for (int r = 0; r < 4; ++r) {
      float s = ss[h][r];
      s += __shfl_xor(s, 1); s += __shfl_xor(s, 2);
      s += __shfl_xor(s, 4); s += __shfl_xor(s, 8);
      if (mrow == 0) atomicAdd(&nc2[m0 + h * 16 + g * 4 + r], s);
      if (t == 0) {
        float sq = yq[h][r];
        sq += __shfl_xor(sq, 1); sq += __shfl_xor(sq, 2);
        sq += __shfl_xor(sq, 4); sq += __shfl_xor(sq, 8);
        if (mrow == 0) atomicAdd(&P.qwacc[m0 + h * 16 + g * 4 + r], sq);
      }
    }
  }
  __syncthreads();   // LDS reused by next task iteration
}

// ============== phase 2: cosine sims, bf16 MFMA, B-tile in LDS ==============
__device__ void phase2_task(const Params& P, char* smem, int task, int tid) {
  ushort_t* lds = (ushort_t*)smem;
  int s = task >> 7;
  const ushort_t* A = (s < 2) ? P.qbe + KP : P.qbc;
  const ushort_t* B = s == 0 ? P.d1be + KP : s == 1 ? P.d2be + KP
                    : s == 2 ? P.d1bc : P.d2bc;
  const float* na2 = (s < 2) ? P.nq2 : P.nqc2;
  const float* nb2 = s == 0 ? P.nd12 : s == 1 ? P.nd22 : s == 2 ? P.nd1c2 : P.nd2c2;
  float* out = P.sims + (size_t)s * QQ * DD;
  int l0 = (task & 127) * 32;
  for (int i = tid; i < 32 * 40; i += 256) {
    int row = i / 40, col = i - row * 40;
    *(short8*)(&lds[row * LDSW + col * 8]) =
        *(const short8*)(B + (size_t)(l0 + row) * KP + col * 8);
  }
  __syncthreads();
  int wv = tid >> 6, lane = tid & 63, mrow = lane & 15, g = lane >> 4;
  f32x4 acc[2];
  acc[0] = (f32x4){0.f, 0.f, 0.f, 0.f};
  acc[1] = (f32x4){0.f, 0.f, 0.f, 0.f};
  const ushort_t* arow = A + (size_t)(wv * 16 + mrow) * KP + g * 8;
  #pragma unroll
  for (int ks = 0; ks < 10; ++ks) {
    short8 a = *(const short8*)(arow + ks * 32);
    #pragma unroll
    for (int n = 0; n < 2; ++n) {
      short8 bfr = *(const short8*)(&lds[(n * 16 + mrow) * LDSW + g * 8 + ks * 32]);
      acc[n] = __builtin_amdgcn_mfma_f32_16x16x32_bf16(a, bfr, acc[n], 0, 0, 0);
    }
  }
  #pragma unroll
  for (int n = 0; n < 2; ++n) {
    int l = l0 + n * 16 + mrow;
    float inb = rsqrtf(nb2[l]);
    #pragma unroll
    for (int r = 0; r < 4; ++r) {
      int q = wv * 16 + g * 4 + r;
      out[(size_t)q * DD + l] = acc[n][r] * rsqrtf(na2[q]) * inb;
    }
  }
  __syncthreads();   // LDS reuse guard
}

// ==================== phase 3: top-5 pooling ([Q][D] rows) ==================
__device__ void phase3_task(const Params& P, char* smem, int task, int tid) {
  float (*ls)[5] = (float(*)[5])smem;
  int q = task & 63, src = task >> 6;
  const size_t QD = (size_t)QQ * DD;
  const float* base;
  switch (src) {
    case 0: base = P.ohT1; break;
    case 1: base = P.sims; break;
    case 2: base = P.sims + 2 * QD; break;
    case 3: base = P.ohT2; break;
    case 4: base = P.sims + QD; break;
    default: base = P.sims + 3 * QD; break;
  }
  const float* row = base + (size_t)q * DD;
  float t5[5];
  #pragma unroll
  for (int j = 0; j < 5; ++j) t5[j] = -1e30f;
  for (int l = tid; l < DD; l += 256) top5_insert(t5, row[l]);
  #pragma unroll
  for (int j = 0; j < 5; ++j) ls[tid][j] = t5[j];
  __syncthreads();
  for (int step = 128; step >= 1; step >>= 1) {
    if (tid < step) {
      float a[5], c[5], m[5];
      #pragma unroll
      for (int j = 0; j < 5; ++j) { a[j] = ls[tid][j]; c[j] = ls[tid + step][j]; }
      int ia = 0, ib = 0;
      #pragma unroll
      for (int j = 0; j < 5; ++j) m[j] = (a[ia] >= c[ib]) ? a[ia++] : c[ib++];
      #pragma unroll
      for (int j = 0; j < 5; ++j) ls[tid][j] = m[j];
    }
    __syncthreads();
  }
  if (tid == 0) {
    float mx = ls[0][0];
    float sm = 0.f;
    #pragma unroll
    for (int j = 0; j < 5; ++j) sm += ls[0][j];
    P.pool[((size_t)src * QQ + q) * 2 + 0] = mx;
    P.pool[((size_t)src * QQ + q) * 2 + 1] = sm * 0.2f;
  }
  __syncthreads();
}

// ============= phase 4: softmax + MLP + epilogue (one wave) =================
__device__ void phase4(const Params& P, int tid) {
  if (tid >= 64) return;
  int q = tid;
  float s = P.qwacc[q] + P.qw_b[0] + P.idf[P.question[q]] * P.qw_w[EE];
  float m = s;
  #pragma unroll
  for (int o = 32; o; o >>= 1) m = fmaxf(m, __shfl_xor(m, o));
  float e = expf(s - m);
  float se = e;
  #pragma unroll
  for (int o = 32; o; o >>= 1) se += __shfl_xor(se, o);
  float qwgt = e / se;

  float emit[2];
  for (int doc = 0; doc < 2; ++doc) {
    float temp[6];
    #pragma unroll
    for (int j = 0; j < 3; ++j) {
      temp[2 * j]     = P.pool[(((size_t)doc * 3 + j) * QQ + q) * 2 + 0];
      temp[2 * j + 1] = P.pool[(((size_t)doc * 3 + j) * QQ + q) * 2 + 1];
    }
    float lo = 0.f;
    #pragma unroll
    for (int r = 0; r < 8; ++r) {
      float h = 0.f;
      #pragma unroll
      for (int c = 0; c < 6; ++c) h += P.lin1_w[r * 6 + c] * temp[c];
      h = (h >= 0.f) ? h : NEG * h;
      lo += P.lin2_w[r] * h;
    }
    lo *= qwgt;
    #pragma unroll
    for (int o = 32; o; o >>= 1) lo += __shfl_xor(lo, o);
    emit[doc] = lo / (float)QQ;
  }
  if (q == 0) {
    float good = P.out_w[0] * P.gaf[0] + P.out_w[1] * P.gaf[1] + P.out_w[2] * P.gaf[2] +
                 P.out_w[3] * P.gaf[3] + P.out_w[4] * emit[0];
    float bad  = P.out_w[0] * P.baf[0] + P.out_w[1] * P.baf[1] + P.out_w[2] * P.baf[2] +
                 P.out_w[3] * P.baf[3] + P.out_w[4] * emit[1];
    float l1 = fmaxf(0.f, -(good - bad) + 1.f);
    P.out5[0] = l1; P.out5[1] = good; P.out5[2] = bad; P.out5[3] = l1; P.out5[4] = l1;
  }
}

// =================== fused cooperative kernel ===============================
__global__ __launch_bounds__(256, 2) void fused(Params P) {
  __shared__ __align__(16) char smem[SMEM_BYTES];
  int tid = threadIdx.x;
  cg::grid_group grid = cg::this_grid();
  for (int task = blockIdx.x; task < N0; task += GRID) phase0_task(P, smem, task, tid);
  grid.sync();
  for (int task = blockIdx.x; task < N1; task += GRID) phase1_task(P, smem, task, tid);
  grid.sync();
  for (int task = blockIdx.x; task < N2; task += GRID) phase2_task(P, smem, task, tid);
  grid.sync();
  for (int task = blockIdx.x; task < N3; task += GRID) phase3_task(P, smem, task, tid);
  grid.sync();
  if (blockIdx.x == 0) phase4(P, tid);
}

// =================== fallback: same phases as 5 kernels =====================
__global__ __launch_bounds__(256) void k0(Params P) {
  __shared__ __align__(16) char smem[SMEM_BYTES];
  phase0_task(P, smem, blockIdx.x, threadIdx.x);
}
__global__ __launch_bounds__(256) void k1(Params P) {
  __shared__ __align__(16) char smem[SMEM_BYTES];
  phase1_task(P, smem, blockIdx.x, threadIdx.x);
}
__global__ __launch_bounds__(256) void k2(Params P) {
  __shared__ __align__(16) char smem[SMEM_BYTES];
  phase2_task(P, smem, blockIdx.x, threadIdx.x);
}
__global__ __launch_bounds__(256) void k3(Params P) {
  __shared__ __align__(16) char smem[SMEM_BYTES];
  phase3_task(P, smem, blockIdx.x, threadIdx.x);
}
__global__ void k4(Params P) { phase4(P, threadIdx.x); }

extern "C" void kernel_launch(void* const* d_in, const int* in_sizes, int n_in,
                              void* d_out, int out_size, void* d_ws, size_t ws_size,
                              hipStream_t stream) {
  (void)in_sizes; (void)n_in; (void)out_size; (void)ws_size;
  Params P;
  P.question = (const int*)d_in[0];
  P.doc1     = (const int*)d_in[1];
  P.doc2     = (const int*)d_in[2];
  P.doc1_sim = (const float*)d_in[3];
  P.doc2_sim = (const float*)d_in[4];
  P.gaf      = (const float*)d_in[5];
  P.baf      = (const float*)d_in[6];
  P.emb      = (const float*)d_in[7];
  P.idf      = (const float*)d_in[8];
  P.conv_w   = (const float*)d_in[9];
  P.conv_b   = (const float*)d_in[10];
  P.qw_w     = (const float*)d_in[11];
  P.qw_b     = (const float*)d_in[12];
  P.lin1_w   = (const float*)d_in[13];
  P.lin2_w   = (const float*)d_in[14];
  P.out_w    = (const float*)d_in[15];
  P.out5     = (float*)d_out;

  char* p = (char*)d_ws;
  P.qbe  = (ushort_t*)p; p += (size_t)(QQ + 2) * KP * 2;
  P.d1be = (ushort_t*)p; p += (size_t)(DD + 2) * KP * 2;
  P.d2be = (ushort_t*)p; p += (size_t)(DD + 2) * KP * 2;
  P.qbc  = (ushort_t*)p; p += (size_t)QQ * KP * 2;
  P.d1bc = (ushort_t*)p; p += (size_t)DD * KP * 2;
  P.d2bc = (ushort_t*)p; p += (size_t)DD * KP * 2;
  P.wt2  = (ushort_t*)p; p += (size_t)570 * 512 * 2;
  P.sims = (float*)p; p += (size_t)4 * QQ * DD * 4;
  P.ohT1 = (float*)p; p += (size_t)QQ * DD * 4;
  P.ohT2 = (float*)p; p += (size_t)QQ * DD * 4;
  P.nq2  = (float*)p; p += QQ * 4;
  P.nd12 = (float*)p; p += DD * 4;
  P.nd22 = (float*)p; p += DD * 4;
  // zeroed-each-call accumulator block (contiguous 8320 floats)
  P.nqc2  = (float*)p; p += QQ * 4;
  P.nd1c2 = (float*)p; p += DD * 4;
  P.nd2c2 = (float*)p; p += DD * 4;
  P.qwacc = (float*)p; p += QQ * 4;
  P.pool  = (float*)p; p += 6 * QQ * 2 * 4;

  void* args[] = {&P};
  hipError_t err = hipLaunchCooperativeKernel(fused, dim3(GRID), dim3(256),
                                              args, (unsigned)0, stream);
  if (err != hipSuccess) {   // fallback: same phases, separate launches
    k0<<<N0, 256, 0, stream>>>(P);
    k1<<<N1, 256, 0, stream>>>(P);
    k2<<<N2, 256, 0, stream>>>(P);
    k3<<<N3, 256, 0, stream>>>(P);
    k4<<<1, 64, 0, stream>>>(P);
  }
}

// Round 6
// 75.939 us; speedup vs baseline: 4.2419x; 4.2419x over previous
//
#include <hip/hip_runtime.h>
#include <math.h>

#define EE 300
#define KP 320     // bf16 row stride (10 k-steps of 32)
#define LDSW 328   // padded LDS row stride in shorts
#define QQ 64
#define DD 4096
#define NEG 0.01f

typedef __attribute__((ext_vector_type(8))) short short8;
typedef __attribute__((ext_vector_type(4))) float f32x4;
typedef unsigned short ushort_t;

__device__ inline ushort_t f2bf(float f) {
  unsigned u = __builtin_bit_cast(unsigned, f);
  u += 0x7fff + ((u >> 16) & 1);   // RNE
  return (ushort_t)(u >> 16);
}
__device__ inline float bf2f(ushort_t h) {
  return __builtin_bit_cast(float, (unsigned)h << 16);
}

// ========== launch 1: weight fragments (+ zero the kmaxf counter) ==========
// wt2[(tap*19+n)*10+ks][lane][8]: B-frag for 16x16x32, lane l holds
// B[k = ks*32+(l>>4)*8+e][col = n*16+(l&15)]
__global__ __launch_bounds__(256) void wtk(const float* __restrict__ w,
                                           ushort_t* __restrict__ wt2,
                                           unsigned* __restrict__ cnt) {
  if (blockIdx.x == 0 && threadIdx.x == 0) *cnt = 0u;
  int f = blockIdx.x * 4 + (threadIdx.x >> 6);
  if (f >= 570) return;
  int lane = threadIdx.x & 63;
  int ks = f % 10, n = (f / 10) % 19, tap = f / 190;
  int o = n * 16 + (lane & 15);
  int kbase = ks * 32 + (lane >> 4) * 8;
  ushort_t* dst = wt2 + (size_t)f * 512 + lane * 8;
  #pragma unroll
  for (int e = 0; e < 8; ++e) {
    int k = kbase + e;
    float v = (o < EE && k < EE) ? w[((size_t)o * EE + k) * 3 + tap] : 0.f;
    dst[e] = f2bf(v);
  }
}

// ========== launch 2: gather + conv1d(E,E,3,SAME)+bias+leaky+residual ======
// One block per 32-row tile (2 q + 128 d1 + 128 d2 = 258 blocks).
// Gathers its 34-row guarded window into LDS (bf16), writes be rows + emb
// norms^2, then 19 n-tiles of MFMA conv; epilogue writes bc + conv norms^2
// (block-local LDS reduce, no atomics) + qw-dot for the question tile.
__global__ __launch_bounds__(256) void gconv(
    const float* __restrict__ emb, const int* __restrict__ question,
    const int* __restrict__ doc1, const int* __restrict__ doc2,
    const ushort_t* __restrict__ wt2, const float* __restrict__ conv_b,
    const float* __restrict__ qw_w,
    ushort_t* __restrict__ qbe, ushort_t* __restrict__ d1be, ushort_t* __restrict__ d2be,
    ushort_t* __restrict__ qbc, ushort_t* __restrict__ d1bc, ushort_t* __restrict__ d2bc,
    float* __restrict__ nq2, float* __restrict__ nd12, float* __restrict__ nd22,
    float* __restrict__ nqc2, float* __restrict__ nd1c2, float* __restrict__ nd2c2,
    float* __restrict__ qwacc) {
  __shared__ ushort_t lds[34 * LDSW];
  __shared__ float normbuf[4][32];
  __shared__ float qwbuf[4][32];
  int bx = blockIdx.x;
  int t, m0;
  if (bx < 2)        { t = 0; m0 = bx * 32; }
  else if (bx < 130) { t = 1; m0 = (bx - 2) * 32; }
  else               { t = 2; m0 = (bx - 130) * 32; }
  int L = t == 0 ? QQ : DD;
  const int* idx = t == 0 ? question : (t == 1 ? doc1 : doc2);
  ushort_t* be = t == 0 ? qbe : (t == 1 ? d1be : d2be);
  ushort_t* bc = t == 0 ? qbc : (t == 1 ? d1bc : d2bc);
  float* ne2 = t == 0 ? nq2 : (t == 1 ? nd12 : nd22);
  float* nc2 = t == 0 ? nqc2 : (t == 1 ? nd1c2 : nd2c2);
  int tid = threadIdx.x, wv = tid >> 6, lane = tid & 63;

  // ---- gather: wave per row, rows rl = wv, wv+4, ... < 34 ----
  #pragma unroll
  for (int it = 0; it < 9; ++it) {
    int rl = wv + it * 4;
    if (rl < 34) {
      int gr = m0 - 1 + rl;                    // global row
      if (gr >= 0 && gr < L) {
        const float* src = emb + (size_t)idx[gr] * EE;
        float ss = 0.f;
        ushort_t hb[5];
        #pragma unroll
        for (int c = 0; c < 5; ++c) {
          int i = lane + c * 64;               // 0..319
          if (i < EE) {
            float v = src[i];
            hb[c] = f2bf(v);
            ss += v * v;
          } else {
            hb[c] = 0;
          }
          lds[rl * LDSW + i] = hb[c];
        }
        if (rl >= 1 && rl <= 32) {             // interior row owned by block
          #pragma unroll
          for (int c = 0; c < 5; ++c) be[(size_t)gr * KP + lane + c * 64] = hb[c];
          #pragma unroll
          for (int o = 32; o; o >>= 1) ss += __shfl_xor(ss, o);
          if (lane == 0) ne2[gr] = ss;         // SQUARED emb-row norm
        }
      } else {
        #pragma unroll
        for (int c = 0; c < 5; ++c) lds[rl * LDSW + lane + c * 64] = 0;
      }
    }
  }
  __syncthreads();

  // ---- conv MFMA: wave wv covers n-tiles [wv*5, wv*5+ncnt) ----
  int nstart = wv * 5, ncnt = (wv == 3) ? 4 : 5;
  int mrow = lane & 15, g = lane >> 4;
  f32x4 acc[5][2];
  #pragma unroll
  for (int j = 0; j < 5; ++j)
    #pragma unroll
    for (int h = 0; h < 2; ++h) acc[j][h] = (f32x4){0.f, 0.f, 0.f, 0.f};

  for (int tap = 0; tap < 3; ++tap) {
    const ushort_t* alo = &lds[(mrow + tap) * LDSW + g * 8];
    #pragma unroll
    for (int ks = 0; ks < 10; ++ks) {
      short8 a0 = *(const short8*)(alo + ks * 32);
      short8 a1 = *(const short8*)(alo + 16 * LDSW + ks * 32);
      #pragma unroll
      for (int j = 0; j < 5; ++j) {
        if (j < ncnt) {
          short8 bfr = *(const short8*)(wt2 +
              (size_t)((tap * 19 + nstart + j) * 10 + ks) * 512 + lane * 8);
          acc[j][0] = __builtin_amdgcn_mfma_f32_16x16x32_bf16(a0, bfr, acc[j][0], 0, 0, 0);
          acc[j][1] = __builtin_amdgcn_mfma_f32_16x16x32_bf16(a1, bfr, acc[j][1], 0, 0, 0);
        }
      }
    }
  }
  // zero bc K-pad cols for this block's rows (needed by sim)
  for (int i = tid; i < 32 * 20; i += 256) {
    int row = i / 20, col = EE + i % 20;
    bc[(size_t)(m0 + row) * KP + col] = 0;
  }
  // epilogue: col = n*16+mrow, row = m0 + h*16 + g*4 + r
  float ssn[2][4] = {{0.f,0.f,0.f,0.f},{0.f,0.f,0.f,0.f}};
  float yq[2][4] = {{0.f,0.f,0.f,0.f},{0.f,0.f,0.f,0.f}};
  #pragma unroll
  for (int j = 0; j < 5; ++j) {
    if (j < ncnt) {
      int col = (nstart + j) * 16 + mrow;
      if (col < EE) {
        float bcol = conv_b[col];
        float qwc = (t == 0) ? qw_w[col] : 0.f;
        #pragma unroll
        for (int h = 0; h < 2; ++h) {
          #pragma unroll
          for (int r = 0; r < 4; ++r) {
            int lrow = h * 16 + g * 4 + r;
            float y = acc[j][h][r] + bcol;
            y = (y >= 0.f) ? y : NEG * y;
            y += bf2f(lds[(1 + lrow) * LDSW + col]);   // residual
            bc[(size_t)(m0 + lrow) * KP + col] = f2bf(y);
            ssn[h][r] += y * y;
            yq[h][r] += y * qwc;
          }
        }
      }
    }
  }
  #pragma unroll
  for (int h = 0; h < 2; ++h) {
    #pragma unroll
    for (int r = 0; r < 4; ++r) {
      float s = ssn[h][r];
      s += __shfl_xor(s, 1); s += __shfl_xor(s, 2);
      s += __shfl_xor(s, 4); s += __shfl_xor(s, 8);
      float sq = yq[h][r];
      sq += __shfl_xor(sq, 1); sq += __shfl_xor(sq, 2);
      sq += __shfl_xor(sq, 4); sq += __shfl_xor(sq, 8);
      if (mrow == 0) {
        normbuf[wv][h * 16 + g * 4 + r] = s;
        qwbuf[wv][h * 16 + g * 4 + r] = sq;
      }
    }
  }
  __syncthreads();
  if (tid < 32) {
    nc2[m0 + tid] = normbuf[0][tid] + normbuf[1][tid] + normbuf[2][tid] + normbuf[3][tid];
    if (t == 0)
      qwacc[m0 + tid] = qwbuf[0][tid] + qwbuf[1][tid] + qwbuf[2][tid] + qwbuf[3][tid];
  }
}

// ========== launch 3: cosine sims (bf16 MFMA, B-tile in LDS) ===============
__global__ __launch_bounds__(256) void sim_mfma(
    const ushort_t* __restrict__ qbe, const ushort_t* __restrict__ d1be,
    const ushort_t* __restrict__ d2be,
    const ushort_t* __restrict__ qbc, const ushort_t* __restrict__ d1bc,
    const ushort_t* __restrict__ d2bc,
    const float* __restrict__ nq2, const float* __restrict__ nd12,
    const float* __restrict__ nd22, const float* __restrict__ nqc2,
    const float* __restrict__ nd1c2, const float* __restrict__ nd2c2,
    float* __restrict__ sims) {
  __shared__ ushort_t lds[32 * LDSW];
  int s = blockIdx.y;
  const ushort_t* A = (s < 2) ? qbe : qbc;
  const ushort_t* B = s == 0 ? d1be : s == 1 ? d2be : s == 2 ? d1bc : d2bc;
  const float* na2 = (s < 2) ? nq2 : nqc2;
  const float* nb2 = s == 0 ? nd12 : s == 1 ? nd22 : s == 2 ? nd1c2 : nd2c2;
  float* out = sims + (size_t)s * QQ * DD;
  int l0 = blockIdx.x * 32;
  int tid = threadIdx.x;
  for (int i = tid; i < 32 * 40; i += 256) {
    int row = i / 40, col = i - row * 40;
    *(short8*)(&lds[row * LDSW + col * 8]) =
        *(const short8*)(B + (size_t)(l0 + row) * KP + col * 8);
  }
  __syncthreads();
  int wv = tid >> 6, lane = tid & 63, mrow = lane & 15, g = lane >> 4;
  f32x4 acc[2];
  acc[0] = (f32x4){0.f, 0.f, 0.f, 0.f};
  acc[1] = (f32x4){0.f, 0.f, 0.f, 0.f};
  const ushort_t* arow = A + (size_t)(wv * 16 + mrow) * KP + g * 8;
  #pragma unroll
  for (int ks = 0; ks < 10; ++ks) {
    short8 a = *(const short8*)(arow + ks * 32);
    #pragma unroll
    for (int n = 0; n < 2; ++n) {
      short8 bfr = *(const short8*)(&lds[(n * 16 + mrow) * LDSW + g * 8 + ks * 32]);
      acc[n] = __builtin_amdgcn_mfma_f32_16x16x32_bf16(a, bfr, acc[n], 0, 0, 0);
    }
  }
  #pragma unroll
  for (int n = 0; n < 2; ++n) {
    int l = l0 + n * 16 + mrow;
    float inb = rsqrtf(nb2[l]);
    #pragma unroll
    for (int r = 0; r < 4; ++r) {
      int q = wv * 16 + g * 4 + r;
      out[(size_t)q * DD + l] = acc[n][r] * rsqrtf(na2[q]) * inb;
    }
  }
}

// ========== launch 4: top-5 pooling + (last block) final epilogue ==========
__device__ inline void top5_insert(float* t, float v) {
  if (v > t[4]) {
    t[4] = v;
    #pragma unroll
    for (int j = 4; j > 0; --j)
      if (t[j] > t[j - 1]) { float tmp = t[j]; t[j] = t[j - 1]; t[j - 1] = tmp; }
  }
}

__global__ __launch_bounds__(256) void kmaxf(
    const float* __restrict__ d1sim, const float* __restrict__ d2sim,
    const float* __restrict__ sims, float* __restrict__ pool,
    unsigned* __restrict__ cnt,
    const float* __restrict__ qwacc, const float* __restrict__ idf,
    const int* __restrict__ question, const float* __restrict__ qw_w,
    const float* __restrict__ qw_b, const float* __restrict__ lin1_w,
    const float* __restrict__ lin2_w, const float* __restrict__ out_w,
    const float* __restrict__ gaf, const float* __restrict__ baf,
    float* __restrict__ out5) {
  __shared__ float ls[256][5];
  __shared__ int islast;
  int q = blockIdx.x & 63, src = blockIdx.x >> 6;
  int tid = threadIdx.x;
  const size_t QD = (size_t)QQ * DD;
  float t5[5];
  #pragma unroll
  for (int j = 0; j < 5; ++j) t5[j] = -1e30f;
  if (src == 0) {
    for (int l = tid; l < DD; l += 256) top5_insert(t5, d1sim[(size_t)l * QQ + q]);
  } else if (src == 3) {
    for (int l = tid; l < DD; l += 256) top5_insert(t5, d2sim[(size_t)l * QQ + q]);
  } else {
    int sidx = src == 1 ? 0 : src == 2 ? 2 : src == 4 ? 1 : 3;
    const float* row = sims + sidx * QD + (size_t)q * DD;
    for (int l = tid; l < DD; l += 256) top5_insert(t5, row[l]);
  }
  #pragma unroll
  for (int j = 0; j < 5; ++j) ls[tid][j] = t5[j];
  __syncthreads();
  for (int step = 128; step >= 1; step >>= 1) {
    if (tid < step) {
      float a[5], c[5], m[5];
      #pragma unroll
      for (int j = 0; j < 5; ++j) { a[j] = ls[tid][j]; c[j] = ls[tid + step][j]; }
      int ia = 0, ib = 0;
      #pragma unroll
      for (int j = 0; j < 5; ++j) m[j] = (a[ia] >= c[ib]) ? a[ia++] : c[ib++];
      #pragma unroll
      for (int j = 0; j < 5; ++j) ls[tid][j] = m[j];
    }
    __syncthreads();
  }
  if (tid == 0) {
    float mx = ls[0][0];
    float sm = 0.f;
    #pragma unroll
    for (int j = 0; j < 5; ++j) sm += ls[0][j];
    pool[((size_t)src * QQ + q) * 2 + 0] = mx;
    pool[((size_t)src * QQ + q) * 2 + 1] = sm * 0.2f;
    __threadfence();                       // release pool write
    unsigned old = atomicAdd(cnt, 1u);     // device-scope
    islast = (old == 383u) ? 1 : 0;
  }
  __syncthreads();
  if (islast) {
    __threadfence();                       // acquire all pool writes
    if (tid < 64) {
      int qq = tid;                        // one wave does the epilogue
      float s = qwacc[qq] + qw_b[0] + idf[question[qq]] * qw_w[EE];
      float m = s;
      #pragma unroll
      for (int o = 32; o; o >>= 1) m = fmaxf(m, __shfl_xor(m, o));
      float e = expf(s - m);
      float se = e;
      #pragma unroll
      for (int o = 32; o; o >>= 1) se += __shfl_xor(se, o);
      float qwgt = e / se;
      float emit[2];
      for (int doc = 0; doc < 2; ++doc) {
        float temp[6];
        #pragma unroll
        for (int j = 0; j < 3; ++j) {
          temp[2 * j]     = pool[(((size_t)doc * 3 + j) * QQ + qq) * 2 + 0];
          temp[2 * j + 1] = pool[(((size_t)doc * 3 + j) * QQ + qq) * 2 + 1];
        }
        float lo = 0.f;
        #pragma unroll
        for (int r = 0; r < 8; ++r) {
          float h = 0.f;
          #pragma unroll
          for (int c = 0; c < 6; ++c) h += lin1_w[r * 6 + c] * temp[c];
          h = (h >= 0.f) ? h : NEG * h;
          lo += lin2_w[r] * h;
        }
        lo *= qwgt;
        #pragma unroll
        for (int o = 32; o; o >>= 1) lo += __shfl_xor(lo, o);
        emit[doc] = lo / (float)QQ;
      }
      if (qq == 0) {
        float good = out_w[0] * gaf[0] + out_w[1] * gaf[1] + out_w[2] * gaf[2] +
                     out_w[3] * gaf[3] + out_w[4] * emit[0];
        float bad  = out_w[0] * baf[0] + out_w[1] * baf[1] + out_w[2] * baf[2] +
                     out_w[3] * baf[3] + out_w[4] * emit[1];
        float l1 = fmaxf(0.f, -(good - bad) + 1.f);
        out5[0] = l1; out5[1] = good; out5[2] = bad; out5[3] = l1; out5[4] = l1;
      }
    }
  }
}

extern "C" void kernel_launch(void* const* d_in, const int* in_sizes, int n_in,
                              void* d_out, int out_size, void* d_ws, size_t ws_size,
                              hipStream_t stream) {
  (void)in_sizes; (void)n_in; (void)out_size; (void)ws_size;
  const int* question   = (const int*)d_in[0];
  const int* doc1       = (const int*)d_in[1];
  const int* doc2       = (const int*)d_in[2];
  const float* doc1_sim = (const float*)d_in[3];
  const float* doc2_sim = (const float*)d_in[4];
  const float* gaf      = (const float*)d_in[5];
  const float* baf      = (const float*)d_in[6];
  const float* emb      = (const float*)d_in[7];
  const float* idf      = (const float*)d_in[8];
  const float* conv_w   = (const float*)d_in[9];
  const float* conv_b   = (const float*)d_in[10];
  const float* qw_w     = (const float*)d_in[11];
  const float* qw_b     = (const float*)d_in[12];
  const float* lin1_w   = (const float*)d_in[13];
  const float* lin2_w   = (const float*)d_in[14];
  const float* out_w    = (const float*)d_in[15];
  float* out = (float*)d_out;

  char* p = (char*)d_ws;
  ushort_t* qbe  = (ushort_t*)p; p += (size_t)QQ * KP * 2;
  ushort_t* d1be = (ushort_t*)p; p += (size_t)DD * KP * 2;
  ushort_t* d2be = (ushort_t*)p; p += (size_t)DD * KP * 2;
  ushort_t* qbc  = (ushort_t*)p; p += (size_t)QQ * KP * 2;
  ushort_t* d1bc = (ushort_t*)p; p += (size_t)DD * KP * 2;
  ushort_t* d2bc = (ushort_t*)p; p += (size_t)DD * KP * 2;
  ushort_t* wt2  = (ushort_t*)p; p += (size_t)570 * 512 * 2;
  float* sims  = (float*)p; p += (size_t)4 * QQ * DD * 4;
  float* nq2   = (float*)p; p += QQ * 4;
  float* nd12  = (float*)p; p += DD * 4;
  float* nd22  = (float*)p; p += DD * 4;
  float* nqc2  = (float*)p; p += QQ * 4;
  float* nd1c2 = (float*)p; p += DD * 4;
  float* nd2c2 = (float*)p; p += DD * 4;
  float* qwacc = (float*)p; p += QQ * 4;
  float* pool  = (float*)p; p += 6 * QQ * 2 * 4;
  unsigned* cnt = (unsigned*)p; p += 4;

  wtk<<<143, 256, 0, stream>>>(conv_w, wt2, cnt);

  gconv<<<258, 256, 0, stream>>>(
      emb, question, doc1, doc2, wt2, conv_b, qw_w,
      qbe, d1be, d2be, qbc, d1bc, d2bc,
      nq2, nd12, nd22, nqc2, nd1c2, nd2c2, qwacc);

  sim_mfma<<<dim3(DD / 32, 4), 256, 0, stream>>>(
      qbe, d1be, d2be, qbc, d1bc, d2bc,
      nq2, nd12, nd22, nqc2, nd1c2, nd2c2, sims);

  kmaxf<<<384, 256, 0, stream>>>(
      doc1_sim, doc2_sim, sims, pool, cnt,
      qwacc, idf, question, qw_w, qw_b, lin1_w, lin2_w, out_w, gaf, baf, out);
}